// Round 17
// baseline (40.800 us; speedup 1.0000x reference)
//
#include <hip/hip_runtime.h>
#include <hip/hip_bf16.h>

#define BSZ   4
#define NG    15135
#define MROWS (BSZ*NG)     // 60540
#define NF    64
#define H     128
#define NCMT  1000
#define NEDGE 100000
#define HFC   256
#define NCLS  10
#define NB2   64           // k2 blocks (x1024 thr)
#define CCH   25

typedef __attribute__((ext_vector_type(8))) short  bfrag;   // 8 bf16 = 4 VGPR
typedef __attribute__((ext_vector_type(4))) float  f32x4;

// hardware packed f32x2 -> bf16x2 (v_cvt_pk_bf16_f32)
__device__ __forceinline__ unsigned int pkbf(float a, float b) {
    union { __hip_bfloat162 h2; unsigned int u; } c;
    c.h2 = __float22bfloat162_rn(make_float2(a, b));
    return c.u;
}

// ---------------------------------------------------------------------------
// kP: pack W1^T/W2^T MFMA-A fragments; init hacc = bl1; zero acc/cnt.
// Measured 0.8us.  (R15 byte-identical.)
// frag layout: elem ((ci*NT + t)*64 + l)*8 + kk = W[t*32+(l>>4)*8+kk][ci*16+(l&15)]
// ---------------------------------------------------------------------------
__global__ __launch_bounds__(256) void kP(const float* __restrict__ W1,
                                          const float* __restrict__ W2,
                                          const float* __restrict__ bl1,
                                          unsigned int* __restrict__ wfrag_u32,
                                          float* __restrict__ hacc,
                                          float* __restrict__ acc,
                                          int* __restrict__ cnt) {
    const int q = blockIdx.x * 256 + threadIdx.x;   // 0..12287
    if (q < BSZ * HFC) hacc[q] = bl1[q & (HFC - 1)];
    if (q < BSZ * NCMT) acc[q] = 0.f;
    if (q < NCMT)       cnt[q] = 0;

    const int e = 2 * q;
    float f0, f1;
    if (e < 8192) {                       // W1 frags: ct = ci*2+t (16)
        const int kk = e & 7, l = (e >> 3) & 63, ct = e >> 9;
        const int t = ct & 1, ci = ct >> 1;
        const int k = t * 32 + (l >> 4) * 8 + kk;
        const int i = ci * 16 + (l & 15);
        f0 = W1[k * H + i];
        f1 = W1[(k + 1) * H + i];
    } else {                              // W2 frags: ct = ci*4+t (32)
        const int e2 = e - 8192;
        const int kk = e2 & 7, l = (e2 >> 3) & 63, ct = e2 >> 9;
        const int t = ct & 3, ci = ct >> 2;
        const int k = t * 32 + (l >> 4) * 8 + kk;
        const int i = ci * 16 + (l & 15);
        f0 = W2[k * H + i];
        f1 = W2[(k + 1) * H + i];
    }
    wfrag_u32[q] = pkbf(f0, f1);
}

// ---------------------------------------------------------------------------
// K1: proven, measured 4.7us.  bf16-MFMA fused MLP + Wfc dot.
// Swapped operands: C[channel][row]. 4 waves x 16 rows = 64 rows/block.
// (R15 byte-identical.)
// ---------------------------------------------------------------------------
__global__ __launch_bounds__(256, 2) void k1_fdot(const float* __restrict__ x,
                                                  const unsigned int* __restrict__ wfrag_g,
                                                  const float* __restrict__ b1,
                                                  const float* __restrict__ b2,
                                                  const float* __restrict__ Wfc,
                                                  float* __restrict__ fdot4) {
    __shared__ unsigned int   wfrag[12288];        // 48KB
    __shared__ unsigned short h1s[4][16][136];     // pad 128->136

    const int tid  = threadIdx.x;
    const int lane = tid & 63, wid = tid >> 6;
    const int sub  = lane & 15, grp = lane >> 4;
    const int r  = blockIdx.x * 64 + wid * 16 + sub;
    const int rc = r < MROWS ? r : MROWS - 1;

    float4 xr[4];
    #pragma unroll
    for (int t = 0; t < 2; ++t) {
        xr[2 * t]     = *(const float4*)&x[(size_t)rc * NF + t * 32 + grp * 8];
        xr[2 * t + 1] = *(const float4*)&x[(size_t)rc * NF + t * 32 + grp * 8 + 4];
    }

    {   // stage fragment weights: straight linear copy (conflict-free)
        const uint4* src = (const uint4*)wfrag_g;
        uint4* dst = (uint4*)wfrag;
        #pragma unroll
        for (int i = 0; i < 12; ++i) dst[i * 256 + tid] = src[i * 256 + tid];
    }
    __syncthreads();

    bfrag bx[2];
    #pragma unroll
    for (int t = 0; t < 2; ++t) {
        union { bfrag v; unsigned int u[4]; } pk;
        const float4 a = xr[2 * t], b = xr[2 * t + 1];
        pk.u[0] = pkbf(a.x, a.y); pk.u[1] = pkbf(a.z, a.w);
        pk.u[2] = pkbf(b.x, b.y); pk.u[3] = pkbf(b.z, b.w);
        bx[t] = pk.v;
    }

    const bfrag* w1f = (const bfrag*)wfrag;
    const bfrag* w2f = (const bfrag*)(wfrag + 4096);
    float fp = 0.f;

    #pragma unroll
    for (int ci = 0; ci < 8; ++ci) {
        f32x4 c1 = {0.f, 0.f, 0.f, 0.f};
        c1 = __builtin_amdgcn_mfma_f32_16x16x32_bf16(w1f[(ci * 2 + 0) * 64 + lane], bx[0], c1, 0, 0, 0);
        c1 = __builtin_amdgcn_mfma_f32_16x16x32_bf16(w1f[(ci * 2 + 1) * 64 + lane], bx[1], c1, 0, 0, 0);
        const int c0 = ci * 16 + grp * 4;
        const float4 b1v = *(const float4*)&b1[c0];
        const float4 wfa = *(const float4*)&Wfc[2 * c0];
        const float4 wfb = *(const float4*)&Wfc[2 * c0 + 4];
        const float h0 = fmaxf(c1[0] + b1v.x, 0.f);
        const float h1 = fmaxf(c1[1] + b1v.y, 0.f);
        const float h2 = fmaxf(c1[2] + b1v.z, 0.f);
        const float h3 = fmaxf(c1[3] + b1v.w, 0.f);
        fp = fmaf(h0, wfa.x, fp); fp = fmaf(h1, wfa.z, fp);
        fp = fmaf(h2, wfb.x, fp); fp = fmaf(h3, wfb.z, fp);
        *(uint2*)&h1s[wid][sub][c0] = make_uint2(pkbf(h0, h1), pkbf(h2, h3));
    }

    bfrag bh[4];
    #pragma unroll
    for (int t = 0; t < 4; ++t)
        bh[t] = *(const bfrag*)&h1s[wid][sub][t * 32 + grp * 8];

    #pragma unroll
    for (int ci = 0; ci < 8; ++ci) {
        f32x4 c2 = {0.f, 0.f, 0.f, 0.f};
        #pragma unroll
        for (int t = 0; t < 4; ++t)
            c2 = __builtin_amdgcn_mfma_f32_16x16x32_bf16(w2f[(ci * 4 + t) * 64 + lane], bh[t], c2, 0, 0, 0);
        const int c0 = ci * 16 + grp * 4;
        const float4 b2v = *(const float4*)&b2[c0];
        const float4 wfa = *(const float4*)&Wfc[2 * c0];
        const float4 wfb = *(const float4*)&Wfc[2 * c0 + 4];
        fp = fmaf(fmaxf(c2[0] + b2v.x, 0.f), wfa.y, fp);
        fp = fmaf(fmaxf(c2[1] + b2v.y, 0.f), wfa.w, fp);
        fp = fmaf(fmaxf(c2[2] + b2v.z, 0.f), wfb.y, fp);
        fp = fmaf(fmaxf(c2[3] + b2v.w, 0.f), wfb.w, fp);
    }

    fp += __shfl_xor(fp, 16);
    fp += __shfl_xor(fp, 32);
    if (grp == 0 && r < MROWS) {
        const int b = r / NG, g = r - b * NG;
        fdot4[g * 4 + b] = fp;
    }
}

// ---------------------------------------------------------------------------
// K2 [the round's ONE change vs R15]: 64 blocks x 1024 threads (same 65K
// threads as 128x512, but 4 waves/SIMD latency hiding and HALF the global
// flush atomics: 640K -> 320K).  LDS privatized scan, native atomics.
// ---------------------------------------------------------------------------
__global__ __launch_bounds__(1024) void k2_scatter(const int* __restrict__ row,
                                                   const int* __restrict__ col,
                                                   const float* __restrict__ fdot4,
                                                   float* __restrict__ acc,
                                                   int* __restrict__ cnt) {
    __shared__ float lacc[4 * NCMT];    // 16 KB
    __shared__ int   lcnt[NCMT];        // 4 KB
    const int tid = threadIdx.x;

    for (int i = tid; i < 4 * NCMT; i += 1024) lacc[i] = 0.f;
    for (int i = tid; i < NCMT; i += 1024) lcnt[i] = 0;
    __syncthreads();

    for (int e = blockIdx.x * 1024 + tid; e < NEDGE; e += NB2 * 1024) {
        const int r = row[e];
        const int c = col[e];
        const float4 f = *(const float4*)&fdot4[r * 4];
        unsafeAtomicAdd(&lacc[c],            f.x);   // ds_add_f32
        unsafeAtomicAdd(&lacc[NCMT + c],     f.y);
        unsafeAtomicAdd(&lacc[2 * NCMT + c], f.z);
        unsafeAtomicAdd(&lacc[3 * NCMT + c], f.w);
        atomicAdd(&lcnt[c], 1);                      // ds_add_u32
    }
    __syncthreads();

    for (int i = tid; i < 4 * NCMT; i += 1024)
        unsafeAtomicAdd(&acc[i], lacc[i]);           // global_atomic_add_f32
    for (int i = tid; i < NCMT; i += 1024)
        atomicAdd(&cnt[i], lcnt[i]);
}

// ---------------------------------------------------------------------------
// K3a: measured ~0.2us.  Scores for 25-col chunk from acc/cnt, GEMV -> hacc.
// (R15 byte-identical.)
// ---------------------------------------------------------------------------
__global__ __launch_bounds__(256) void k3a_head1(const float* __restrict__ acc,
                                                 const int* __restrict__ cnt,
                                                 const float* __restrict__ bfc,
                                                 const float* __restrict__ Wl1,
                                                 float* __restrict__ hacc) {
    __shared__ float sc[BSZ][CCH];
    const int c0 = blockIdx.x * CCH;
    const int t = threadIdx.x;

    if (t < BSZ * CCH) {
        const int b = t / CCH, cc = t % CCH;
        const int c = c0 + cc;
        sc[b][cc] = acc[b * NCMT + c] / fmaxf((float)cnt[c], 1.f) + bfc[0];
    }
    __syncthreads();

    float p0 = 0.f, p1 = 0.f, p2 = 0.f, p3 = 0.f;
    #pragma unroll
    for (int cc = 0; cc < CCH; ++cc) {
        const float wv = Wl1[(size_t)(c0 + cc) * HFC + t];
        p0 = fmaf(sc[0][cc], wv, p0);
        p1 = fmaf(sc[1][cc], wv, p1);
        p2 = fmaf(sc[2][cc], wv, p2);
        p3 = fmaf(sc[3][cc], wv, p3);
    }
    unsafeAtomicAdd(&hacc[0 * HFC + t], p0);
    unsafeAtomicAdd(&hacc[1 * HFC + t], p1);
    unsafeAtomicAdd(&hacc[2 * HFC + t], p2);
    unsafeAtomicAdd(&hacc[3 * HFC + t], p3);
}

// ---------------------------------------------------------------------------
// K3b: proven head (LDS-staged parallel GEMV + log_softmax).  (R15 identical.)
// ---------------------------------------------------------------------------
__global__ __launch_bounds__(256) void k3b_head2(const float* __restrict__ hacc,
                                                 const float* __restrict__ Wl2,
                                                 const float* __restrict__ bl2,
                                                 float* __restrict__ out) {
    __shared__ float wl2s[HFC][NCLS + 2];
    __shared__ float hr[BSZ][HFC + 4];
    __shared__ float part[BSZ][NCLS][6];
    __shared__ float lg[BSZ][NCLS];
    const int t = threadIdx.x;

    #pragma unroll
    for (int i = t; i < HFC * NCLS; i += 256)
        wl2s[i / NCLS][i % NCLS] = Wl2[i];
    #pragma unroll
    for (int q = 0; q < BSZ; ++q)
        hr[q][t] = fmaxf(hacc[q * HFC + t], 0.f);
    __syncthreads();

    if (t < BSZ * NCLS * 6) {
        const int b = t / (NCLS * 6), rem = t % (NCLS * 6);
        const int k = rem / 6, ch = rem % 6;
        const int j0 = ch * 43;
        const int j1 = (j0 + 43 > HFC) ? HFC : j0 + 43;
        float p = 0.f;
        for (int j = j0; j < j1; ++j)
            p = fmaf(hr[b][j], wl2s[j][k], p);
        part[b][k][ch] = p;
    }
    __syncthreads();

    if (t < BSZ * NCLS) {
        const int b = t / NCLS, k = t % NCLS;
        float a = bl2[k];
        #pragma unroll
        for (int ch = 0; ch < 6; ++ch) a += part[b][k][ch];
        lg[b][k] = a;
    }
    __syncthreads();
    if (t < BSZ * NCLS) {
        const int b = t / NCLS, k = t % NCLS;
        float m = lg[b][0];
        #pragma unroll
        for (int k2 = 1; k2 < NCLS; ++k2) m = fmaxf(m, lg[b][k2]);
        float s = 0.f;
        #pragma unroll
        for (int k2 = 0; k2 < NCLS; ++k2) s += expf(lg[b][k2] - m);
        out[b * NCLS + k] = lg[b][k] - m - logf(s);
    }
}

// ---------------------------------------------------------------------------
extern "C" void kernel_launch(void* const* d_in, const int* in_sizes, int n_in,
                              void* d_out, int out_size, void* d_ws, size_t ws_size,
                              hipStream_t stream) {
    const float* x   = (const float*)d_in[0];
    // d_in[1] = batch (unused)
    const int*   row = (const int*)d_in[2];
    const int*   col = (const int*)d_in[3];
    const float* W1  = (const float*)d_in[4];
    const float* b1  = (const float*)d_in[5];
    const float* W2  = (const float*)d_in[6];
    const float* b2  = (const float*)d_in[7];
    const float* Wfc = (const float*)d_in[8];
    const float* bfc = (const float*)d_in[9];
    const float* Wl1 = (const float*)d_in[10];
    const float* bl1 = (const float*)d_in[11];
    const float* Wl2 = (const float*)d_in[12];
    const float* bl2 = (const float*)d_in[13];

    float* ws    = (float*)d_ws;
    float* fdot4 = ws;                                   // 60544 floats
    float* acc   = ws + 60544;                           // 4000
    int*   cnt   = (int*)(ws + 64544);                   // 1000
    float* hacc  = ws + 65544;                           // 1024
    unsigned int* wfrag = (unsigned int*)(ws + 66568);   // 12288 u32

    kP<<<48, 256, 0, stream>>>(W1, W2, bl1, wfrag, hacc, acc, cnt);
    k1_fdot<<<(MROWS + 63) / 64, 256, 0, stream>>>(x, wfrag, b1, b2, Wfc, fdot4);
    k2_scatter<<<NB2, 1024, 0, stream>>>(row, col, fdot4, acc, cnt);
    k3a_head1<<<NCMT / CCH, 256, 0, stream>>>(acc, cnt, bfc, Wl1, hacc);
    k3b_head2<<<1, 256, 0, stream>>>(hacc, Wl2, bl2, (float*)d_out);
}

// Round 18
// 36.574 us; speedup vs baseline: 1.1156x; 1.1156x over previous
//
#include <hip/hip_runtime.h>
#include <hip/hip_bf16.h>

#define BSZ   4
#define NG    15135
#define MROWS (BSZ*NG)     // 60540
#define NF    64
#define H     128
#define NCMT  1000
#define NEDGE 100000
#define HFC   256
#define NCLS  10
#define NB2   128          // k2 blocks (x512 thr) — A/B-proven optimum (R17)
#define CCH   25

typedef __attribute__((ext_vector_type(8))) short  bfrag;   // 8 bf16 = 4 VGPR
typedef __attribute__((ext_vector_type(4))) float  f32x4;

// hardware packed f32x2 -> bf16x2 (v_cvt_pk_bf16_f32)
__device__ __forceinline__ unsigned int pkbf(float a, float b) {
    union { __hip_bfloat162 h2; unsigned int u; } c;
    c.h2 = __float22bfloat162_rn(make_float2(a, b));
    return c.u;
}

// ---------------------------------------------------------------------------
// kP: pack W1^T/W2^T MFMA-A fragments; init hacc = bl1; zero acc/cnt
// (re-zeroed every call -> graph-replay safe).  Measured ~0.8us.
// frag layout: elem ((ci*NT + t)*64 + l)*8 + kk = W[t*32+(l>>4)*8+kk][ci*16+(l&15)]
// ---------------------------------------------------------------------------
__global__ __launch_bounds__(256) void kP(const float* __restrict__ W1,
                                          const float* __restrict__ W2,
                                          const float* __restrict__ bl1,
                                          unsigned int* __restrict__ wfrag_u32,
                                          float* __restrict__ hacc,
                                          float* __restrict__ acc,
                                          int* __restrict__ cnt) {
    const int q = blockIdx.x * 256 + threadIdx.x;   // 0..12287
    if (q < BSZ * HFC) hacc[q] = bl1[q & (HFC - 1)];
    if (q < BSZ * NCMT) acc[q] = 0.f;
    if (q < NCMT)       cnt[q] = 0;

    const int e = 2 * q;
    float f0, f1;
    if (e < 8192) {                       // W1 frags: ct = ci*2+t (16)
        const int kk = e & 7, l = (e >> 3) & 63, ct = e >> 9;
        const int t = ct & 1, ci = ct >> 1;
        const int k = t * 32 + (l >> 4) * 8 + kk;
        const int i = ci * 16 + (l & 15);
        f0 = W1[k * H + i];
        f1 = W1[(k + 1) * H + i];
    } else {                              // W2 frags: ct = ci*4+t (32)
        const int e2 = e - 8192;
        const int kk = e2 & 7, l = (e2 >> 3) & 63, ct = e2 >> 9;
        const int t = ct & 3, ci = ct >> 2;
        const int k = t * 32 + (l >> 4) * 8 + kk;
        const int i = ci * 16 + (l & 15);
        f0 = W2[k * H + i];
        f1 = W2[(k + 1) * H + i];
    }
    wfrag_u32[q] = pkbf(f0, f1);
}

// ---------------------------------------------------------------------------
// K1: proven, measured 4.7us.  bf16-MFMA fused MLP + Wfc dot.
// Swapped operands: C[channel][row]. 4 waves x 16 rows = 64 rows/block.
// ---------------------------------------------------------------------------
__global__ __launch_bounds__(256, 2) void k1_fdot(const float* __restrict__ x,
                                                  const unsigned int* __restrict__ wfrag_g,
                                                  const float* __restrict__ b1,
                                                  const float* __restrict__ b2,
                                                  const float* __restrict__ Wfc,
                                                  float* __restrict__ fdot4) {
    __shared__ unsigned int   wfrag[12288];        // 48KB
    __shared__ unsigned short h1s[4][16][136];     // pad 128->136

    const int tid  = threadIdx.x;
    const int lane = tid & 63, wid = tid >> 6;
    const int sub  = lane & 15, grp = lane >> 4;
    const int r  = blockIdx.x * 64 + wid * 16 + sub;
    const int rc = r < MROWS ? r : MROWS - 1;

    float4 xr[4];
    #pragma unroll
    for (int t = 0; t < 2; ++t) {
        xr[2 * t]     = *(const float4*)&x[(size_t)rc * NF + t * 32 + grp * 8];
        xr[2 * t + 1] = *(const float4*)&x[(size_t)rc * NF + t * 32 + grp * 8 + 4];
    }

    {   // stage fragment weights: straight linear copy (conflict-free)
        const uint4* src = (const uint4*)wfrag_g;
        uint4* dst = (uint4*)wfrag;
        #pragma unroll
        for (int i = 0; i < 12; ++i) dst[i * 256 + tid] = src[i * 256 + tid];
    }
    __syncthreads();

    bfrag bx[2];
    #pragma unroll
    for (int t = 0; t < 2; ++t) {
        union { bfrag v; unsigned int u[4]; } pk;
        const float4 a = xr[2 * t], b = xr[2 * t + 1];
        pk.u[0] = pkbf(a.x, a.y); pk.u[1] = pkbf(a.z, a.w);
        pk.u[2] = pkbf(b.x, b.y); pk.u[3] = pkbf(b.z, b.w);
        bx[t] = pk.v;
    }

    const bfrag* w1f = (const bfrag*)wfrag;
    const bfrag* w2f = (const bfrag*)(wfrag + 4096);
    float fp = 0.f;

    #pragma unroll
    for (int ci = 0; ci < 8; ++ci) {
        f32x4 c1 = {0.f, 0.f, 0.f, 0.f};
        c1 = __builtin_amdgcn_mfma_f32_16x16x32_bf16(w1f[(ci * 2 + 0) * 64 + lane], bx[0], c1, 0, 0, 0);
        c1 = __builtin_amdgcn_mfma_f32_16x16x32_bf16(w1f[(ci * 2 + 1) * 64 + lane], bx[1], c1, 0, 0, 0);
        const int c0 = ci * 16 + grp * 4;
        const float4 b1v = *(const float4*)&b1[c0];
        const float4 wfa = *(const float4*)&Wfc[2 * c0];
        const float4 wfb = *(const float4*)&Wfc[2 * c0 + 4];
        const float h0 = fmaxf(c1[0] + b1v.x, 0.f);
        const float h1 = fmaxf(c1[1] + b1v.y, 0.f);
        const float h2 = fmaxf(c1[2] + b1v.z, 0.f);
        const float h3 = fmaxf(c1[3] + b1v.w, 0.f);
        fp = fmaf(h0, wfa.x, fp); fp = fmaf(h1, wfa.z, fp);
        fp = fmaf(h2, wfb.x, fp); fp = fmaf(h3, wfb.z, fp);
        *(uint2*)&h1s[wid][sub][c0] = make_uint2(pkbf(h0, h1), pkbf(h2, h3));
    }

    bfrag bh[4];
    #pragma unroll
    for (int t = 0; t < 4; ++t)
        bh[t] = *(const bfrag*)&h1s[wid][sub][t * 32 + grp * 8];

    #pragma unroll
    for (int ci = 0; ci < 8; ++ci) {
        f32x4 c2 = {0.f, 0.f, 0.f, 0.f};
        #pragma unroll
        for (int t = 0; t < 4; ++t)
            c2 = __builtin_amdgcn_mfma_f32_16x16x32_bf16(w2f[(ci * 4 + t) * 64 + lane], bh[t], c2, 0, 0, 0);
        const int c0 = ci * 16 + grp * 4;
        const float4 b2v = *(const float4*)&b2[c0];
        const float4 wfa = *(const float4*)&Wfc[2 * c0];
        const float4 wfb = *(const float4*)&Wfc[2 * c0 + 4];
        fp = fmaf(fmaxf(c2[0] + b2v.x, 0.f), wfa.y, fp);
        fp = fmaf(fmaxf(c2[1] + b2v.y, 0.f), wfa.w, fp);
        fp = fmaf(fmaxf(c2[2] + b2v.z, 0.f), wfb.y, fp);
        fp = fmaf(fmaxf(c2[3] + b2v.w, 0.f), wfb.w, fp);
    }

    fp += __shfl_xor(fp, 16);
    fp += __shfl_xor(fp, 32);
    if (grp == 0 && r < MROWS) {
        const int b = r / NG, g = r - b * NG;
        fdot4[g * 4 + b] = fp;
    }
}

// ---------------------------------------------------------------------------
// K2: measured 6.7us at this geometry (A/B-proven vs 64x1024 = 10.9us).
// 128 blocks x 512 thr, LDS privatized scan, flush via native global fp/int
// atomics into kP-zeroed acc/cnt (no partial buffer).
// ---------------------------------------------------------------------------
__global__ __launch_bounds__(512) void k2_scatter(const int* __restrict__ row,
                                                  const int* __restrict__ col,
                                                  const float* __restrict__ fdot4,
                                                  float* __restrict__ acc,
                                                  int* __restrict__ cnt) {
    __shared__ float lacc[4 * NCMT];    // 16 KB
    __shared__ int   lcnt[NCMT];        // 4 KB
    const int tid = threadIdx.x;

    for (int i = tid; i < 4 * NCMT; i += 512) lacc[i] = 0.f;
    for (int i = tid; i < NCMT; i += 512) lcnt[i] = 0;
    __syncthreads();

    for (int e = blockIdx.x * 512 + tid; e < NEDGE; e += NB2 * 512) {
        const int r = row[e];
        const int c = col[e];
        const float4 f = *(const float4*)&fdot4[r * 4];
        unsafeAtomicAdd(&lacc[c],            f.x);   // ds_add_f32
        unsafeAtomicAdd(&lacc[NCMT + c],     f.y);
        unsafeAtomicAdd(&lacc[2 * NCMT + c], f.z);
        unsafeAtomicAdd(&lacc[3 * NCMT + c], f.w);
        atomicAdd(&lcnt[c], 1);                      // ds_add_u32
    }
    __syncthreads();

    for (int i = tid; i < 4 * NCMT; i += 512)
        unsafeAtomicAdd(&acc[i], lacc[i]);           // global_atomic_add_f32
    for (int i = tid; i < NCMT; i += 512)
        atomicAdd(&cnt[i], lcnt[i]);
}

// ---------------------------------------------------------------------------
// K3a: measured ~0.2us.  Scores for 25-col chunk from acc/cnt, GEMV -> hacc.
// ---------------------------------------------------------------------------
__global__ __launch_bounds__(256) void k3a_head1(const float* __restrict__ acc,
                                                 const int* __restrict__ cnt,
                                                 const float* __restrict__ bfc,
                                                 const float* __restrict__ Wl1,
                                                 float* __restrict__ hacc) {
    __shared__ float sc[BSZ][CCH];
    const int c0 = blockIdx.x * CCH;
    const int t = threadIdx.x;

    if (t < BSZ * CCH) {
        const int b = t / CCH, cc = t % CCH;
        const int c = c0 + cc;
        sc[b][cc] = acc[b * NCMT + c] / fmaxf((float)cnt[c], 1.f) + bfc[0];
    }
    __syncthreads();

    float p0 = 0.f, p1 = 0.f, p2 = 0.f, p3 = 0.f;
    #pragma unroll
    for (int cc = 0; cc < CCH; ++cc) {
        const float wv = Wl1[(size_t)(c0 + cc) * HFC + t];
        p0 = fmaf(sc[0][cc], wv, p0);
        p1 = fmaf(sc[1][cc], wv, p1);
        p2 = fmaf(sc[2][cc], wv, p2);
        p3 = fmaf(sc[3][cc], wv, p3);
    }
    unsafeAtomicAdd(&hacc[0 * HFC + t], p0);
    unsafeAtomicAdd(&hacc[1 * HFC + t], p1);
    unsafeAtomicAdd(&hacc[2 * HFC + t], p2);
    unsafeAtomicAdd(&hacc[3 * HFC + t], p3);
}

// ---------------------------------------------------------------------------
// K3b: proven head (LDS-staged parallel GEMV + log_softmax), ~1.5us.
// ---------------------------------------------------------------------------
__global__ __launch_bounds__(256) void k3b_head2(const float* __restrict__ hacc,
                                                 const float* __restrict__ Wl2,
                                                 const float* __restrict__ bl2,
                                                 float* __restrict__ out) {
    __shared__ float wl2s[HFC][NCLS + 2];
    __shared__ float hr[BSZ][HFC + 4];
    __shared__ float part[BSZ][NCLS][6];
    __shared__ float lg[BSZ][NCLS];
    const int t = threadIdx.x;

    #pragma unroll
    for (int i = t; i < HFC * NCLS; i += 256)
        wl2s[i / NCLS][i % NCLS] = Wl2[i];
    #pragma unroll
    for (int q = 0; q < BSZ; ++q)
        hr[q][t] = fmaxf(hacc[q * HFC + t], 0.f);
    __syncthreads();

    if (t < BSZ * NCLS * 6) {
        const int b = t / (NCLS * 6), rem = t % (NCLS * 6);
        const int k = rem / 6, ch = rem % 6;
        const int j0 = ch * 43;
        const int j1 = (j0 + 43 > HFC) ? HFC : j0 + 43;
        float p = 0.f;
        for (int j = j0; j < j1; ++j)
            p = fmaf(hr[b][j], wl2s[j][k], p);
        part[b][k][ch] = p;
    }
    __syncthreads();

    if (t < BSZ * NCLS) {
        const int b = t / NCLS, k = t % NCLS;
        float a = bl2[k];
        #pragma unroll
        for (int ch = 0; ch < 6; ++ch) a += part[b][k][ch];
        lg[b][k] = a;
    }
    __syncthreads();
    if (t < BSZ * NCLS) {
        const int b = t / NCLS, k = t % NCLS;
        float m = lg[b][0];
        #pragma unroll
        for (int k2 = 1; k2 < NCLS; ++k2) m = fmaxf(m, lg[b][k2]);
        float s = 0.f;
        #pragma unroll
        for (int k2 = 0; k2 < NCLS; ++k2) s += expf(lg[b][k2] - m);
        out[b * NCLS + k] = lg[b][k] - m - logf(s);
    }
}

// ---------------------------------------------------------------------------
extern "C" void kernel_launch(void* const* d_in, const int* in_sizes, int n_in,
                              void* d_out, int out_size, void* d_ws, size_t ws_size,
                              hipStream_t stream) {
    const float* x   = (const float*)d_in[0];
    // d_in[1] = batch (unused)
    const int*   row = (const int*)d_in[2];
    const int*   col = (const int*)d_in[3];
    const float* W1  = (const float*)d_in[4];
    const float* b1  = (const float*)d_in[5];
    const float* W2  = (const float*)d_in[6];
    const float* b2  = (const float*)d_in[7];
    const float* Wfc = (const float*)d_in[8];
    const float* bfc = (const float*)d_in[9];
    const float* Wl1 = (const float*)d_in[10];
    const float* bl1 = (const float*)d_in[11];
    const float* Wl2 = (const float*)d_in[12];
    const float* bl2 = (const float*)d_in[13];

    float* ws    = (float*)d_ws;
    float* fdot4 = ws;                                   // 60544 floats
    float* acc   = ws + 60544;                           // 4000
    int*   cnt   = (int*)(ws + 64544);                   // 1000
    float* hacc  = ws + 65544;                           // 1024
    unsigned int* wfrag = (unsigned int*)(ws + 66568);   // 12288 u32

    kP<<<48, 256, 0, stream>>>(W1, W2, bl1, wfrag, hacc, acc, cnt);
    k1_fdot<<<(MROWS + 63) / 64, 256, 0, stream>>>(x, wfrag, b1, b2, Wfc, fdot4);
    k2_scatter<<<NB2, 512, 0, stream>>>(row, col, fdot4, acc, cnt);
    k3a_head1<<<NCMT / CCH, 256, 0, stream>>>(acc, cnt, bfc, Wl1, hacc);
    k3b_head2<<<1, 256, 0, stream>>>(hacc, Wl2, bl2, (float*)d_out);
}